// Round 2
// baseline (348.348 us; speedup 1.0000x reference)
//
#include <hip/hip_runtime.h>
#include <hip/hip_bf16.h>

// RNN cell: out[B,N] = tanh( concat(x,hidden)[B,K] @ W^T[K,N] + b[N] )
// M=16384, N=1024, K=2048 (K-halves: x then hidden), fp32 in/out.
// bf16 MFMA GEMM, fused fp32->bf16 conversion in reg->LDS staging,
// 2-phase software pipeline (issue t+1 loads under t's MFMA phase).

typedef __bf16 bf16_t;
typedef __bf16 bf16x8 __attribute__((ext_vector_type(8)));
typedef float  f32x4  __attribute__((ext_vector_type(4)));

#define BM 128
#define BN 128
#define BK 64
#define NT 32            // K_GLOBAL / BK
#define M_GLOBAL 16384
#define N_GLOBAL 1024
#define IN_STRIDE 1024   // x / hidden row stride (f32 elems)
#define W_STRIDE  2048   // W row stride (f32 elems)

__device__ __forceinline__ float fast_tanh(float v) {
    // tanh(x) = 1 - 2/(e^{2x}+1); exp->inf gives +1, exp->0 gives -1.
    float e = __expf(2.0f * v);
    return 1.0f - 2.0f * __builtin_amdgcn_rcpf(e + 1.0f);
}

__global__ __launch_bounds__(256, 3)
void rnncell_gemm(const float* __restrict__ x, const float* __restrict__ h,
                  const float* __restrict__ W, const float* __restrict__ bias,
                  float* __restrict__ out)
{
    // LDS tiles [128 rows][64 k] bf16, 128B/row. 16B slots XOR-swizzled by
    // (row&7) so ds_read_b128 of a 16-row column-slice is 2-way (free).
    __shared__ __align__(16) bf16_t As[BM * BK];
    __shared__ __align__(16) bf16_t Bs[BN * BK];

    const int tid = threadIdx.x;
    const int bid = blockIdx.x;
    // XCD-aware: bid%8 -> XCD; each XCD owns one N-column; its 1MB W-panel
    // stays L2-resident for the whole kernel.
    const int bm = (bid >> 3) * BM;
    const int bn = (bid & 7) * BN;

    const int lane = tid & 63;
    const int wid  = tid >> 6;
    const int wr = (wid >> 1) * 64;   // wave row offset in tile
    const int wc = (wid & 1) * 64;    // wave col offset in tile
    const int lr = lane & 15;         // frag row/col within 16
    const int lk = lane >> 4;         // k-group 0..3 (8 contiguous k each)

    // staging unit geometry: unit = 8 consecutive f32 (one bf16x8 LDS slot);
    // 1024 units per operand tile, 4 per thread.
    const int row0 = tid >> 3;          // rows tid/8, +32 per i
    const int sl0  = tid & 7;

    f32x4 acc[4][4];
#pragma unroll
    for (int i = 0; i < 4; ++i)
#pragma unroll
        for (int j = 0; j < 4; ++j)
            acc[i][j] = (f32x4){0.f, 0.f, 0.f, 0.f};

    float4 la[4][2], lb[4][2];

#define LOAD_A(T) do {                                                        \
    const int k0_ = (T) * BK;                                                 \
    const float* sA_ = (k0_ < 1024)                                           \
        ? (x + (size_t)bm * IN_STRIDE + k0_)                                  \
        : (h + (size_t)bm * IN_STRIDE + (k0_ - 1024));                        \
    _Pragma("unroll")                                                         \
    for (int i_ = 0; i_ < 4; ++i_) {                                          \
        const float* pa_ = sA_ + (size_t)(row0 + i_ * 32) * IN_STRIDE + sl0 * 8; \
        la[i_][0] = *(const float4*)(pa_);                                    \
        la[i_][1] = *(const float4*)(pa_ + 4);                                \
    }                                                                         \
} while (0)

#define LOAD_B(T) do {                                                        \
    const float* sB_ = W + (size_t)bn * W_STRIDE + (T) * BK;                  \
    _Pragma("unroll")                                                         \
    for (int i_ = 0; i_ < 4; ++i_) {                                          \
        const float* pb_ = sB_ + (size_t)(row0 + i_ * 32) * W_STRIDE + sl0 * 8; \
        lb[i_][0] = *(const float4*)(pb_);                                    \
        lb[i_][1] = *(const float4*)(pb_ + 4);                                \
    }                                                                         \
} while (0)

    // prologue: issue t=0 loads
    LOAD_A(0);
    LOAD_B(0);

    for (int t = 0; t < NT; ++t) {
        // ---- consume in-flight regs: cvt fp32->bf16, swizzled ds_write
#pragma unroll
        for (int i = 0; i < 4; ++i) {
            const int row = row0 + i * 32;
            const int ssl = sl0 ^ (row & 7);
            bf16x8 va, vb;
            va[0] = (bf16_t)la[i][0].x; va[1] = (bf16_t)la[i][0].y;
            va[2] = (bf16_t)la[i][0].z; va[3] = (bf16_t)la[i][0].w;
            va[4] = (bf16_t)la[i][1].x; va[5] = (bf16_t)la[i][1].y;
            va[6] = (bf16_t)la[i][1].z; va[7] = (bf16_t)la[i][1].w;
            vb[0] = (bf16_t)lb[i][0].x; vb[1] = (bf16_t)lb[i][0].y;
            vb[2] = (bf16_t)lb[i][0].z; vb[3] = (bf16_t)lb[i][0].w;
            vb[4] = (bf16_t)lb[i][1].x; vb[5] = (bf16_t)lb[i][1].y;
            vb[6] = (bf16_t)lb[i][1].z; vb[7] = (bf16_t)lb[i][1].w;
            *(bf16x8*)(As + row * BK + ssl * 8) = va;
            *(bf16x8*)(Bs + row * BK + ssl * 8) = vb;
        }

        __syncthreads();   // tile visible to all waves

        // ---- prefetch next A (HBM/L3, long latency) under the MFMA phase
        if (t + 1 < NT) LOAD_A(t + 1);

        // ---- compute: 2 k-halves x 4x4 frags of 16x16x32
#pragma unroll
        for (int kk = 0; kk < 2; ++kk) {
            bf16x8 af[4], bfr[4];
#pragma unroll
            for (int mf = 0; mf < 4; ++mf) {
                const int row = wr + mf * 16 + lr;
                const int sl  = (kk * 4 + lk) ^ (row & 7);
                af[mf] = *(const bf16x8*)(As + row * BK + sl * 8);
            }
#pragma unroll
            for (int nf = 0; nf < 4; ++nf) {
                const int row = wc + nf * 16 + lr;
                const int sl  = (kk * 4 + lk) ^ (row & 7);
                bfr[nf] = *(const bf16x8*)(Bs + row * BK + sl * 8);
            }
#pragma unroll
            for (int mf = 0; mf < 4; ++mf)
#pragma unroll
                for (int nf = 0; nf < 4; ++nf)
                    acc[mf][nf] = __builtin_amdgcn_mfma_f32_16x16x32_bf16(
                        af[mf], bfr[nf], acc[mf][nf], 0, 0, 0);
        }

        // ---- prefetch next B (W-panel is L2-resident, short latency)
        if (t + 1 < NT) LOAD_B(t + 1);

        __syncthreads();   // all waves done reading before next overwrite
    }

#undef LOAD_A
#undef LOAD_B

    // ---- epilogue: bias + tanh, fp32 store
    // C/D layout (verified m89/m91): col = lane&15, row = (lane>>4)*4 + reg
    float bv[4];
#pragma unroll
    for (int nf = 0; nf < 4; ++nf)
        bv[nf] = bias[bn + wc + nf * 16 + lr];
#pragma unroll
    for (int mf = 0; mf < 4; ++mf) {
#pragma unroll
        for (int nf = 0; nf < 4; ++nf) {
            const int col = bn + wc + nf * 16 + lr;
#pragma unroll
            for (int r = 0; r < 4; ++r) {
                const int row = bm + wr + mf * 16 + lk * 4 + r;
                out[(size_t)row * N_GLOBAL + col] = fast_tanh(acc[mf][nf][r] + bv[nf]);
            }
        }
    }
}

extern "C" void kernel_launch(void* const* d_in, const int* in_sizes, int n_in,
                              void* d_out, int out_size, void* d_ws, size_t ws_size,
                              hipStream_t stream) {
    (void)in_sizes; (void)n_in; (void)d_ws; (void)ws_size; (void)out_size;
    const float* x = (const float*)d_in[0];
    const float* h = (const float*)d_in[1];
    const float* W = (const float*)d_in[2];
    const float* b = (const float*)d_in[3];
    float* out = (float*)d_out;
    dim3 grid((M_GLOBAL / BM) * (N_GLOBAL / BN));  // 128 * 8 = 1024
    rnncell_gemm<<<grid, 256, 0, stream>>>(x, h, W, b, out);
}

// Round 3
// 168.869 us; speedup vs baseline: 2.0628x; 2.0628x over previous
//
#include <hip/hip_runtime.h>
#include <hip/hip_bf16.h>

// RNN cell: out[B,N] = tanh( concat(x,hidden)[B,K] @ W^T[K,N] + b[N] )
// M=16384, N=1024, K=2048 (K-halves: x then hidden), fp32 in/out.
// bf16 MFMA GEMM, fused fp32->bf16 conversion in reg->LDS staging,
// software pipeline: t+1 global loads in flight under t's MFMA phase.
// Double-buffered LDS -> single barrier per K-tile.

typedef __bf16 bf16_t;
typedef __bf16 bf16x8 __attribute__((ext_vector_type(8)));
typedef float  f32x4  __attribute__((ext_vector_type(4)));

#define BM 128
#define BN 128
#define BK 64
#define NT 32            // K_GLOBAL / BK
#define M_GLOBAL 16384
#define N_GLOBAL 1024
#define IN_STRIDE 1024   // x / hidden row stride (f32 elems)
#define W_STRIDE  2048   // W row stride (f32 elems)

__device__ __forceinline__ float fast_tanh(float v) {
    // tanh(x) = 1 - 2/(e^{2x}+1); exp->inf gives +1, exp->0 gives -1.
    float e = __expf(2.0f * v);
    return 1.0f - 2.0f * __builtin_amdgcn_rcpf(e + 1.0f);
}

// NOTE register budget (round-2 lesson): acc=64 + staged la/lb=64 + frags=32
// + addressing ~40 => ~200 regs/wave. (256,2) caps at 256 -> no spill.
// (256,3) capped at ~170 and spilled ~330MB of scratch writes per dispatch.
__global__ __launch_bounds__(256, 2)
void rnncell_gemm(const float* __restrict__ x, const float* __restrict__ h,
                  const float* __restrict__ W, const float* __restrict__ bias,
                  float* __restrict__ out)
{
    // LDS tiles [128 rows][64 k] bf16, 128B/row, double-buffered.
    // 16B slots XOR-swizzled by (row&7): ds_read_b128 of a 16-row
    // column-slice is 2-way (free) instead of 8-way.
    __shared__ __align__(16) bf16_t As[2][BM * BK];
    __shared__ __align__(16) bf16_t Bs[2][BM * BK];

    const int tid = threadIdx.x;
    const int bid = blockIdx.x;
    // XCD-aware: bid%8 -> XCD; each XCD owns one N-column; its 1MB W-panel
    // stays L2-resident; concurrent blocks across XCDs share m-tiles via L3.
    const int bm = (bid >> 3) * BM;
    const int bn = (bid & 7) * BN;

    const int lane = tid & 63;
    const int wid  = tid >> 6;
    const int wr = (wid >> 1) * 64;   // wave row offset in tile
    const int wc = (wid & 1) * 64;    // wave col offset in tile
    const int lr = lane & 15;         // frag row/col within 16
    const int lk = lane >> 4;         // k-group 0..3 (8 contiguous k each)

    // staging: unit = 8 consecutive f32 (one bf16x8 LDS slot);
    // 1024 units per operand tile, 4 per thread (rows tid/8 + 32*i).
    const int row0 = tid >> 3;
    const int sl0  = tid & 7;

    f32x4 acc[4][4];
#pragma unroll
    for (int i = 0; i < 4; ++i)
#pragma unroll
        for (int j = 0; j < 4; ++j)
            acc[i][j] = (f32x4){0.f, 0.f, 0.f, 0.f};

    float4 la[4][2], lb[4][2];

#define LOAD_A(T) do {                                                        \
    const int k0_ = (T) * BK;                                                 \
    const float* sA_ = (k0_ < 1024)                                           \
        ? (x + (size_t)bm * IN_STRIDE + k0_)                                  \
        : (h + (size_t)bm * IN_STRIDE + (k0_ - 1024));                        \
    _Pragma("unroll")                                                         \
    for (int i_ = 0; i_ < 4; ++i_) {                                          \
        const float* pa_ = sA_ + (size_t)(row0 + i_ * 32) * IN_STRIDE + sl0 * 8; \
        la[i_][0] = *(const float4*)(pa_);                                    \
        la[i_][1] = *(const float4*)(pa_ + 4);                                \
    }                                                                         \
} while (0)

#define LOAD_B(T) do {                                                        \
    const float* sB_ = W + (size_t)bn * W_STRIDE + (T) * BK;                  \
    _Pragma("unroll")                                                         \
    for (int i_ = 0; i_ < 4; ++i_) {                                          \
        const float* pb_ = sB_ + (size_t)(row0 + i_ * 32) * W_STRIDE + sl0 * 8; \
        lb[i_][0] = *(const float4*)(pb_);                                    \
        lb[i_][1] = *(const float4*)(pb_ + 4);                                \
    }                                                                         \
} while (0)

    // prologue: issue t=0 loads
    LOAD_A(0);
    LOAD_B(0);

    for (int t = 0; t < NT; ++t) {
        bf16_t* __restrict__ Ab = As[t & 1];
        bf16_t* __restrict__ Bb = Bs[t & 1];

        // ---- consume in-flight regs: cvt fp32->bf16, swizzled ds_write.
        // A first (its loads were issued earliest), then B.
#pragma unroll
        for (int i = 0; i < 4; ++i) {
            const int row = row0 + i * 32;
            const int ssl = sl0 ^ (row & 7);
            bf16x8 va;
            va[0] = (bf16_t)la[i][0].x; va[1] = (bf16_t)la[i][0].y;
            va[2] = (bf16_t)la[i][0].z; va[3] = (bf16_t)la[i][0].w;
            va[4] = (bf16_t)la[i][1].x; va[5] = (bf16_t)la[i][1].y;
            va[6] = (bf16_t)la[i][1].z; va[7] = (bf16_t)la[i][1].w;
            *(bf16x8*)(Ab + row * BK + ssl * 8) = va;
        }
#pragma unroll
        for (int i = 0; i < 4; ++i) {
            const int row = row0 + i * 32;
            const int ssl = sl0 ^ (row & 7);
            bf16x8 vb;
            vb[0] = (bf16_t)lb[i][0].x; vb[1] = (bf16_t)lb[i][0].y;
            vb[2] = (bf16_t)lb[i][0].z; vb[3] = (bf16_t)lb[i][0].w;
            vb[4] = (bf16_t)lb[i][1].x; vb[5] = (bf16_t)lb[i][1].y;
            vb[6] = (bf16_t)lb[i][1].z; vb[7] = (bf16_t)lb[i][1].w;
            *(bf16x8*)(Bb + row * BK + ssl * 8) = vb;
        }

        // Single barrier per iter: makes buf[t&1] visible. The next write to
        // buf[t&1] happens only after the t+1 barrier, which every reader of
        // this buffer must reach first -> no second barrier needed.
        __syncthreads();

        // ---- prefetch next A (HBM/L3, long latency) under the MFMA phase
        if (t + 1 < NT) LOAD_A(t + 1);

        // ---- compute: 2 k-halves x 4x4 frags of 16x16x32
#pragma unroll
        for (int kk = 0; kk < 2; ++kk) {
            bf16x8 af[4], bfr[4];
#pragma unroll
            for (int mf = 0; mf < 4; ++mf) {
                const int row = wr + mf * 16 + lr;
                const int sl  = (kk * 4 + lk) ^ (row & 7);
                af[mf] = *(const bf16x8*)(Ab + row * BK + sl * 8);
            }
#pragma unroll
            for (int nf = 0; nf < 4; ++nf) {
                const int row = wc + nf * 16 + lr;
                const int sl  = (kk * 4 + lk) ^ (row & 7);
                bfr[nf] = *(const bf16x8*)(Bb + row * BK + sl * 8);
            }
#pragma unroll
            for (int mf = 0; mf < 4; ++mf)
#pragma unroll
                for (int nf = 0; nf < 4; ++nf)
                    acc[mf][nf] = __builtin_amdgcn_mfma_f32_16x16x32_bf16(
                        af[mf], bfr[nf], acc[mf][nf], 0, 0, 0);
        }

        // ---- prefetch next B (W-panel is L2-resident, short latency;
        // lands during next iter's A-cvt phase)
        if (t + 1 < NT) LOAD_B(t + 1);
    }

#undef LOAD_A
#undef LOAD_B

    // ---- epilogue: bias + tanh, fp32 store
    // C/D layout (verified m89/m91): col = lane&15, row = (lane>>4)*4 + reg
    float bv[4];
#pragma unroll
    for (int nf = 0; nf < 4; ++nf)
        bv[nf] = bias[bn + wc + nf * 16 + lr];
#pragma unroll
    for (int mf = 0; mf < 4; ++mf) {
#pragma unroll
        for (int nf = 0; nf < 4; ++nf) {
            const int col = bn + wc + nf * 16 + lr;
#pragma unroll
            for (int r = 0; r < 4; ++r) {
                const int row = bm + wr + mf * 16 + lk * 4 + r;
                out[(size_t)row * N_GLOBAL + col] = fast_tanh(acc[mf][nf][r] + bv[nf]);
            }
        }
    }
}

extern "C" void kernel_launch(void* const* d_in, const int* in_sizes, int n_in,
                              void* d_out, int out_size, void* d_ws, size_t ws_size,
                              hipStream_t stream) {
    (void)in_sizes; (void)n_in; (void)d_ws; (void)ws_size; (void)out_size;
    const float* x = (const float*)d_in[0];
    const float* h = (const float*)d_in[1];
    const float* W = (const float*)d_in[2];
    const float* b = (const float*)d_in[3];
    float* out = (float*)d_out;
    dim3 grid((M_GLOBAL / BM) * (N_GLOBAL / BN));  // 128 * 8 = 1024
    rnncell_gemm<<<grid, 256, 0, stream>>>(x, h, W, b, out);
}

// Round 4
// 167.691 us; speedup vs baseline: 2.0773x; 1.0070x over previous
//
#include <hip/hip_runtime.h>
#include <hip/hip_bf16.h>

// RNN cell: out[B,N] = tanh( concat(x,hidden)[B,K] @ W^T[K,N] + b[N] )
// M=16384, N=1024, K=2048 (K-halves: x then hidden), fp32 in/out.
// bf16 MFMA GEMM, fused fp32->bf16 conversion in reg->LDS staging.
// 256x128 tile, BK=32, 4 waves (each 128x64), 2-buffer LDS, 1 barrier/iter.
// Pipeline: [cvt+write t] barrier [issue loads t+1] [compute t]
//  - loads issued AFTER barrier so the compiler's pre-barrier vmcnt(0)
//    drain never waits on them; they land under the compute phase.
// Row stride 64B (32 bf16) => ds_read_b128 frag reads and linear ds_writes
// are naturally bank-conflict-free (each bank exactly 8 requests/wave).

typedef __bf16 bf16_t;
typedef __bf16 bf16x8 __attribute__((ext_vector_type(8)));
typedef float  f32x4  __attribute__((ext_vector_type(4)));

#define BM 256
#define BN 128
#define BK 32
#define NT 64            // K_GLOBAL / BK
#define M_GLOBAL 16384
#define N_GLOBAL 1024
#define IN_STRIDE 1024   // x / hidden row stride (f32 elems)
#define W_STRIDE  2048   // W row stride (f32 elems)

__device__ __forceinline__ float fast_tanh(float v) {
    // tanh(x) = 1 - 2/(e^{2x}+1); exp->inf gives +1, exp->0 gives -1.
    float e = __expf(2.0f * v);
    return 1.0f - 2.0f * __builtin_amdgcn_rcpf(e + 1.0f);
}

// Register budget (round-2 lesson): acc 128 (AGPR) + staged la/lb 48 +
// frags ~24 + addr ~35 => ~240 <= 256 cap at (256,2). Watch WRITE_SIZE
// for spill signature.
__global__ __launch_bounds__(256, 2)
void rnncell_gemm(const float* __restrict__ x, const float* __restrict__ h,
                  const float* __restrict__ W, const float* __restrict__ bias,
                  float* __restrict__ out)
{
    __shared__ __align__(16) bf16_t As[2][BM * BK];   // 2 x 16 KB
    __shared__ __align__(16) bf16_t Bs[2][BN * BK];   // 2 x  8 KB

    const int tid = threadIdx.x;
    const int bid = blockIdx.x;
    // bid&7 -> n-tile AND XCD (round-robin dispatch): each XCD owns one
    // 128-col W panel (1 MB fp32, L2-resident). Consecutive bids 8m..8m+7
    // share the A-panel and run concurrently -> L3 dedups A refetch.
    const int bm = (bid >> 3) * BM;
    const int bn = (bid & 7) * BN;

    const int lane = tid & 63;
    const int wid  = tid >> 6;
    const int wr = (wid >> 1) * 128;  // wave row offset (2M x 2N wave grid)
    const int wc = (wid & 1) * 64;    // wave col offset
    const int lr = lane & 15;         // frag row within 16
    const int lk = lane >> 4;         // k-slot 0..3 (8 contiguous k each)

    // staging: unit = 8 consecutive f32 -> one bf16x8 LDS slot.
    // unit u: row = u>>2, slot = u&3. Thread handles u = tid + i*256.
    const int arow = tid >> 2;        // + 64*i
    const int asl  = tid & 3;

    f32x4 acc[8][4];
#pragma unroll
    for (int i = 0; i < 8; ++i)
#pragma unroll
        for (int j = 0; j < 4; ++j)
            acc[i][j] = (f32x4){0.f, 0.f, 0.f, 0.f};

    float4 la[4][2], lb[2][2];

#define LOAD(T) do {                                                          \
    const int k0_ = (T) * BK;                                                 \
    const float* sA_ = (k0_ < 1024)                                           \
        ? (x + (size_t)bm * IN_STRIDE + k0_)                                  \
        : (h + (size_t)bm * IN_STRIDE + (k0_ - 1024));                        \
    _Pragma("unroll")                                                         \
    for (int i_ = 0; i_ < 4; ++i_) {                                          \
        const float* p_ = sA_ + (size_t)(arow + i_ * 64) * IN_STRIDE + asl * 8; \
        la[i_][0] = *(const float4*)(p_);                                     \
        la[i_][1] = *(const float4*)(p_ + 4);                                 \
    }                                                                         \
    const float* sB_ = W + (size_t)bn * W_STRIDE + k0_;                       \
    _Pragma("unroll")                                                         \
    for (int i_ = 0; i_ < 2; ++i_) {                                          \
        const float* p_ = sB_ + (size_t)(arow + i_ * 64) * W_STRIDE + asl * 8; \
        lb[i_][0] = *(const float4*)(p_);                                     \
        lb[i_][1] = *(const float4*)(p_ + 4);                                 \
    }                                                                         \
} while (0)

    // prologue: issue t=0 loads
    LOAD(0);

    for (int t = 0; t < NT; ++t) {
        bf16_t* __restrict__ Ab = As[t & 1];
        bf16_t* __restrict__ Bb = Bs[t & 1];

        // ---- phase 1: cvt fp32->bf16, linear ds_write (conflict-free)
#pragma unroll
        for (int i = 0; i < 4; ++i) {
            bf16x8 v;
            v[0] = (bf16_t)la[i][0].x; v[1] = (bf16_t)la[i][0].y;
            v[2] = (bf16_t)la[i][0].z; v[3] = (bf16_t)la[i][0].w;
            v[4] = (bf16_t)la[i][1].x; v[5] = (bf16_t)la[i][1].y;
            v[6] = (bf16_t)la[i][1].z; v[7] = (bf16_t)la[i][1].w;
            *(bf16x8*)(Ab + (arow + i * 64) * BK + asl * 8) = v;
        }
#pragma unroll
        for (int i = 0; i < 2; ++i) {
            bf16x8 v;
            v[0] = (bf16_t)lb[i][0].x; v[1] = (bf16_t)lb[i][0].y;
            v[2] = (bf16_t)lb[i][0].z; v[3] = (bf16_t)lb[i][0].w;
            v[4] = (bf16_t)lb[i][1].x; v[5] = (bf16_t)lb[i][1].y;
            v[6] = (bf16_t)lb[i][1].z; v[7] = (bf16_t)lb[i][1].w;
            *(bf16x8*)(Bb + (arow + i * 64) * BK + asl * 8) = v;
        }

        // ---- phase 2: barrier (only lgkm drain needed; vmcnt already 0)
        __syncthreads();

        // ---- phase 3: issue next tile's global loads (land under compute)
        if (t + 1 < NT) LOAD(t + 1);

        // ---- phase 4: compute. 12 ds_read_b128 + 32 MFMA (K=32 in one shot)
        bf16x8 bfr[4];
#pragma unroll
        for (int nf = 0; nf < 4; ++nf) {
            const int row = wc + nf * 16 + lr;
            bfr[nf] = *(const bf16x8*)(Bb + row * BK + lk * 8);
        }
#pragma unroll
        for (int mf = 0; mf < 8; ++mf) {
            const int row = wr + mf * 16 + lr;
            bf16x8 af = *(const bf16x8*)(Ab + row * BK + lk * 8);
#pragma unroll
            for (int nf = 0; nf < 4; ++nf)
                acc[mf][nf] = __builtin_amdgcn_mfma_f32_16x16x32_bf16(
                    af, bfr[nf], acc[mf][nf], 0, 0, 0);
        }
        // WAR note: next write to this buffer is 2 iters away, separated by
        // the next barrier -> 2 buffers + 1 barrier/iter is race-free.
    }

#undef LOAD

    // ---- epilogue: bias + tanh, fp32 store
    // C/D layout (verified m89/m91): col = lane&15, row = (lane>>4)*4 + reg
    float bv[4];
#pragma unroll
    for (int nf = 0; nf < 4; ++nf)
        bv[nf] = bias[bn + wc + nf * 16 + lr];
#pragma unroll
    for (int mf = 0; mf < 8; ++mf) {
#pragma unroll
        for (int nf = 0; nf < 4; ++nf) {
            const int col = bn + wc + nf * 16 + lr;
#pragma unroll
            for (int r = 0; r < 4; ++r) {
                const int row = bm + wr + mf * 16 + lk * 4 + r;
                out[(size_t)row * N_GLOBAL + col] = fast_tanh(acc[mf][nf][r] + bv[nf]);
            }
        }
    }
}

extern "C" void kernel_launch(void* const* d_in, const int* in_sizes, int n_in,
                              void* d_out, int out_size, void* d_ws, size_t ws_size,
                              hipStream_t stream) {
    (void)in_sizes; (void)n_in; (void)d_ws; (void)ws_size; (void)out_size;
    const float* x = (const float*)d_in[0];
    const float* h = (const float*)d_in[1];
    const float* W = (const float*)d_in[2];
    const float* b = (const float*)d_in[3];
    float* out = (float*)d_out;
    dim3 grid((M_GLOBAL / BM) * (N_GLOBAL / BN));  // 64 * 8 = 512
    rnncell_gemm<<<grid, 256, 0, stream>>>(x, h, W, b, out);
}

// Round 5
// 130.159 us; speedup vs baseline: 2.6763x; 1.2884x over previous
//
#include <hip/hip_runtime.h>
#include <hip/hip_bf16.h>

// RNN cell: out[B,N] = tanh( concat(x,hidden)[B,K] @ W^T[K,N] + b[N] )
// M=16384, N=1024, K=2048, fp32 in/out.
// Two-pass: (1) fp32->bf16 cvt+concat into ws; (2) m97-structure bf16 MFMA
// GEMM with global_load_lds width-16 staging (the verified 874-TF structure).

typedef __bf16 bf16_t;
typedef __bf16 bf16x8 __attribute__((ext_vector_type(8)));
typedef float  f32x4  __attribute__((ext_vector_type(4)));

#define M_GLOBAL 16384
#define N_GLOBAL 1024
#define K_GLOBAL 2048
#define IN_STRIDE 1024   // x / hidden row stride (f32 elems)

__device__ __forceinline__ float fast_tanh(float v) {
    // tanh(x) = 1 - 2/(e^{2x}+1); exp->inf gives +1, exp->0 gives -1.
    float e = __expf(2.0f * v);
    return 1.0f - 2.0f * __builtin_amdgcn_rcpf(e + 1.0f);
}

// ---------------------------------------------------------------------------
// Pass 1: cvt + concat. XHb[M][2048] = [x | h] in bf16; Wb[N][2048] = W bf16.
// ---------------------------------------------------------------------------
#define XH_UNITS ((long long)M_GLOBAL * K_GLOBAL / 8)   // 4194304 units of 8
#define W_UNITS  ((long long)N_GLOBAL * K_GLOBAL / 8)   //  262144

__global__ __launch_bounds__(256)
void cvt_pass(const float* __restrict__ x, const float* __restrict__ h,
              const float* __restrict__ W,
              bf16_t* __restrict__ XHb, bf16_t* __restrict__ Wb)
{
    const long long total = XH_UNITS + W_UNITS;
    for (long long u = (long long)blockIdx.x * 256 + threadIdx.x; u < total;
         u += (long long)gridDim.x * 256) {
        const float* src;
        bf16_t* dst;
        if (u < XH_UNITS) {
            const long long e = u * 8;
            const int row = (int)(e >> 11);
            const int col = (int)(e & 2047);
            src = (col < 1024) ? (x + (long long)row * IN_STRIDE + col)
                               : (h + (long long)row * IN_STRIDE + (col - 1024));
            dst = XHb + e;
        } else {
            const long long e = (u - XH_UNITS) * 8;
            src = W + e;       // W is [N][2048] contiguous
            dst = Wb + e;
        }
        const float4 v0 = *(const float4*)src;
        const float4 v1 = *(const float4*)(src + 4);
        bf16x8 o;
        o[0] = (bf16_t)v0.x; o[1] = (bf16_t)v0.y;
        o[2] = (bf16_t)v0.z; o[3] = (bf16_t)v0.w;
        o[4] = (bf16_t)v1.x; o[5] = (bf16_t)v1.y;
        o[6] = (bf16_t)v1.z; o[7] = (bf16_t)v1.w;
        *(bf16x8*)dst = o;
    }
}

// ---------------------------------------------------------------------------
// Pass 2: m97-structure GEMM. 128x128 tile, BK=64, 4 waves (64x64 each),
// global_load_lds width 16, linear LDS, 2 barriers per K-step.
// ---------------------------------------------------------------------------
#define BM 128
#define BN 128
#define BK 64
#define NT (K_GLOBAL / BK)   // 32

__device__ __forceinline__ void gload_lds16(const bf16_t* g, bf16_t* l) {
    __builtin_amdgcn_global_load_lds(
        (const __attribute__((address_space(1))) void*)g,
        (__attribute__((address_space(3))) void*)l, 16, 0, 0);
}

__global__ __launch_bounds__(256, 3)
void gemm_bt(const bf16_t* __restrict__ XHb, const bf16_t* __restrict__ Wb,
             const float* __restrict__ bias, float* __restrict__ out)
{
    __shared__ __align__(16) bf16_t As[BM * BK];   // 16 KB, linear [128][64]
    __shared__ __align__(16) bf16_t Bs[BN * BK];   // 16 KB

    const int tid = threadIdx.x;
    const int bid = blockIdx.x;
    // bid&7 -> n-tile AND XCD (round-robin): each XCD's 512 KB Wb panel is
    // L2-resident; concurrent bids 8m..8m+7 share the XHb panel via L3.
    const int bm = (bid >> 3) * BM;
    const int bn = (bid & 7) * BN;

    const int lane = tid & 63;
    const int wid  = tid >> 6;
    const int wr = (wid >> 1) * 64;   // wave row offset
    const int wc = (wid & 1) * 64;    // wave col offset
    const int lr = lane & 15;         // frag row within 16
    const int lk = lane >> 4;         // k-slot 0..3 (8 contiguous k each)

    // staging geometry: chunk = 8 rows x 64 cols = 1 KB, one gload_lds16 per
    // wave per chunk; lane l covers row chunk*8 + (l>>3), cols (l&7)*8..+7.
    // LDS dest is wave-uniform (chunk*512 elems) + lane*16B -> linear layout.
    const int rw8 = lane >> 3;          // row within chunk
    const int kb8 = (lane & 7) * 8;     // col within chunk

    f32x4 acc[4][4];
#pragma unroll
    for (int i = 0; i < 4; ++i)
#pragma unroll
        for (int j = 0; j < 4; ++j)
            acc[i][j] = (f32x4){0.f, 0.f, 0.f, 0.f};

    const bf16_t* aBase = XHb + (size_t)(bm + rw8) * K_GLOBAL + kb8;
    const bf16_t* bBase = Wb  + (size_t)(bn + rw8) * K_GLOBAL + kb8;

    for (int t = 0; t < NT; ++t) {
        const int k0 = t * BK;
        // ---- stage tile t: 4 A-chunks + 4 B-chunks per wave
#pragma unroll
        for (int j = 0; j < 4; ++j) {
            const int c = wid * 4 + j;          // chunk 0..15
            gload_lds16(aBase + (size_t)(c * 8) * K_GLOBAL + k0, As + c * 512);
            gload_lds16(bBase + (size_t)(c * 8) * K_GLOBAL + k0, Bs + c * 512);
        }
        __syncthreads();   // drains vmcnt(0): tile resident + visible

        // ---- compute: 2 k-halves x 4x4 frags of 16x16x32
#pragma unroll
        for (int kk = 0; kk < 2; ++kk) {
            bf16x8 af[4], bfr[4];
#pragma unroll
            for (int mf = 0; mf < 4; ++mf)
                af[mf] = *(const bf16x8*)(As + (wr + mf * 16 + lr) * BK + kk * 32 + lk * 8);
#pragma unroll
            for (int nf = 0; nf < 4; ++nf)
                bfr[nf] = *(const bf16x8*)(Bs + (wc + nf * 16 + lr) * BK + kk * 32 + lk * 8);
#pragma unroll
            for (int mf = 0; mf < 4; ++mf)
#pragma unroll
                for (int nf = 0; nf < 4; ++nf)
                    acc[mf][nf] = __builtin_amdgcn_mfma_f32_16x16x32_bf16(
                        af[mf], bfr[nf], acc[mf][nf], 0, 0, 0);
        }
        __syncthreads();   // all waves done reading before next overwrite
    }

    // ---- epilogue: bias + tanh, fp32 store
    // C/D layout (verified m89/m91 + rounds 1-4): col=lane&15, row=(lane>>4)*4+reg
    float bv[4];
#pragma unroll
    for (int nf = 0; nf < 4; ++nf)
        bv[nf] = bias[bn + wc + nf * 16 + lr];
#pragma unroll
    for (int mf = 0; mf < 4; ++mf) {
#pragma unroll
        for (int nf = 0; nf < 4; ++nf) {
            const int col = bn + wc + nf * 16 + lr;
#pragma unroll
            for (int r = 0; r < 4; ++r) {
                const int row = bm + wr + mf * 16 + lk * 4 + r;
                out[(size_t)row * N_GLOBAL + col] = fast_tanh(acc[mf][nf][r] + bv[nf]);
            }
        }
    }
}

// ---------------------------------------------------------------------------
// Fallback (ws too small): round-3 verified fused kernel (169 us).
// ---------------------------------------------------------------------------
#define FNT 32
__global__ __launch_bounds__(256, 2)
void rnncell_fused(const float* __restrict__ x, const float* __restrict__ h,
                   const float* __restrict__ W, const float* __restrict__ bias,
                   float* __restrict__ out)
{
    __shared__ __align__(16) bf16_t As[2][128 * 64];
    __shared__ __align__(16) bf16_t Bs[2][128 * 64];

    const int tid = threadIdx.x;
    const int bid = blockIdx.x;
    const int bm = (bid >> 3) * 128;
    const int bn = (bid & 7) * 128;

    const int lane = tid & 63;
    const int wid  = tid >> 6;
    const int wr = (wid >> 1) * 64;
    const int wc = (wid & 1) * 64;
    const int lr = lane & 15;
    const int lk = lane >> 4;

    const int row0 = tid >> 3;
    const int sl0  = tid & 7;

    f32x4 acc[4][4];
#pragma unroll
    for (int i = 0; i < 4; ++i)
#pragma unroll
        for (int j = 0; j < 4; ++j)
            acc[i][j] = (f32x4){0.f, 0.f, 0.f, 0.f};

    float4 la[4][2], lb[4][2];

#define F_LOAD_A(T) do {                                                      \
    const int k0_ = (T) * 64;                                                 \
    const float* sA_ = (k0_ < 1024)                                           \
        ? (x + (size_t)bm * IN_STRIDE + k0_)                                  \
        : (h + (size_t)bm * IN_STRIDE + (k0_ - 1024));                        \
    _Pragma("unroll")                                                         \
    for (int i_ = 0; i_ < 4; ++i_) {                                          \
        const float* pa_ = sA_ + (size_t)(row0 + i_ * 32) * IN_STRIDE + sl0 * 8; \
        la[i_][0] = *(const float4*)(pa_);                                    \
        la[i_][1] = *(const float4*)(pa_ + 4);                                \
    }                                                                         \
} while (0)

#define F_LOAD_B(T) do {                                                      \
    const float* sB_ = W + (size_t)bn * K_GLOBAL + (T) * 64;                  \
    _Pragma("unroll")                                                         \
    for (int i_ = 0; i_ < 4; ++i_) {                                          \
        const float* pb_ = sB_ + (size_t)(row0 + i_ * 32) * K_GLOBAL + sl0 * 8; \
        lb[i_][0] = *(const float4*)(pb_);                                    \
        lb[i_][1] = *(const float4*)(pb_ + 4);                                \
    }                                                                         \
} while (0)

    F_LOAD_A(0);
    F_LOAD_B(0);

    for (int t = 0; t < FNT; ++t) {
        bf16_t* __restrict__ Ab = As[t & 1];
        bf16_t* __restrict__ Bb = Bs[t & 1];

#pragma unroll
        for (int i = 0; i < 4; ++i) {
            const int row = row0 + i * 32;
            const int ssl = sl0 ^ (row & 7);
            bf16x8 va;
            va[0] = (bf16_t)la[i][0].x; va[1] = (bf16_t)la[i][0].y;
            va[2] = (bf16_t)la[i][0].z; va[3] = (bf16_t)la[i][0].w;
            va[4] = (bf16_t)la[i][1].x; va[5] = (bf16_t)la[i][1].y;
            va[6] = (bf16_t)la[i][1].z; va[7] = (bf16_t)la[i][1].w;
            *(bf16x8*)(Ab + row * 64 + ssl * 8) = va;
        }
#pragma unroll
        for (int i = 0; i < 4; ++i) {
            const int row = row0 + i * 32;
            const int ssl = sl0 ^ (row & 7);
            bf16x8 vb;
            vb[0] = (bf16_t)lb[i][0].x; vb[1] = (bf16_t)lb[i][0].y;
            vb[2] = (bf16_t)lb[i][0].z; vb[3] = (bf16_t)lb[i][0].w;
            vb[4] = (bf16_t)lb[i][1].x; vb[5] = (bf16_t)lb[i][1].y;
            vb[6] = (bf16_t)lb[i][1].z; vb[7] = (bf16_t)lb[i][1].w;
            *(bf16x8*)(Bb + row * 64 + ssl * 8) = vb;
        }

        __syncthreads();

        if (t + 1 < FNT) F_LOAD_A(t + 1);

#pragma unroll
        for (int kk = 0; kk < 2; ++kk) {
            bf16x8 af[4], bfr[4];
#pragma unroll
            for (int mf = 0; mf < 4; ++mf) {
                const int row = wr + mf * 16 + lr;
                const int sl  = (kk * 4 + lk) ^ (row & 7);
                af[mf] = *(const bf16x8*)(Ab + row * 64 + sl * 8);
            }
#pragma unroll
            for (int nf = 0; nf < 4; ++nf) {
                const int row = wc + nf * 16 + lr;
                const int sl  = (kk * 4 + lk) ^ (row & 7);
                bfr[nf] = *(const bf16x8*)(Bb + row * 64 + sl * 8);
            }
#pragma unroll
            for (int mf = 0; mf < 4; ++mf)
#pragma unroll
                for (int nf = 0; nf < 4; ++nf)
                    acc[mf][nf] = __builtin_amdgcn_mfma_f32_16x16x32_bf16(
                        af[mf], bfr[nf], acc[mf][nf], 0, 0, 0);
        }

        if (t + 1 < FNT) F_LOAD_B(t + 1);
    }
#undef F_LOAD_A
#undef F_LOAD_B

    float bv[4];
#pragma unroll
    for (int nf = 0; nf < 4; ++nf)
        bv[nf] = bias[bn + wc + nf * 16 + lr];
#pragma unroll
    for (int mf = 0; mf < 4; ++mf) {
#pragma unroll
        for (int nf = 0; nf < 4; ++nf) {
            const int col = bn + wc + nf * 16 + lr;
#pragma unroll
            for (int r = 0; r < 4; ++r) {
                const int row = bm + wr + mf * 16 + lk * 4 + r;
                out[(size_t)row * N_GLOBAL + col] = fast_tanh(acc[mf][nf][r] + bv[nf]);
            }
        }
    }
}

extern "C" void kernel_launch(void* const* d_in, const int* in_sizes, int n_in,
                              void* d_out, int out_size, void* d_ws, size_t ws_size,
                              hipStream_t stream) {
    (void)in_sizes; (void)n_in; (void)out_size;
    const float* x = (const float*)d_in[0];
    const float* h = (const float*)d_in[1];
    const float* W = (const float*)d_in[2];
    const float* b = (const float*)d_in[3];
    float* out = (float*)d_out;

    const size_t need = ((size_t)M_GLOBAL + N_GLOBAL) * K_GLOBAL * sizeof(bf16_t);
    if (ws_size >= need) {
        bf16_t* XHb = (bf16_t*)d_ws;
        bf16_t* Wb  = XHb + (size_t)M_GLOBAL * K_GLOBAL;
        cvt_pass<<<2048, 256, 0, stream>>>(x, h, W, XHb, Wb);
        dim3 grid((M_GLOBAL / BM) * (N_GLOBAL / BN));  // 128*8 = 1024
        gemm_bt<<<grid, 256, 0, stream>>>(XHb, Wb, b, out);
    } else {
        rnncell_fused<<<1024, 256, 0, stream>>>(x, h, W, b, out);
    }
}

// Round 7
// 101.307 us; speedup vs baseline: 3.4385x; 1.2848x over previous
//
#include <hip/hip_runtime.h>
#include <hip/hip_bf16.h>

// RNN cell: out[B,N] = tanh( concat(x,hidden)[B,K] @ W^T[K,N] + b[N] )
// M=16384, N=1024, K=2048, fp32 in/out.
// Pass 1: fp32->bf16 cvt+concat into ws (XHb[M][2048], Wb[N][2048]).
// Pass 2: 256x256 8-phase bf16 MFMA GEMM (m201-style: T2 swizzle + T3/T4
//         counted-vmcnt pipeline + T5 setprio), global_load_lds width-16.
// (Round-6 run died with an infra container error before any dispatch
//  counters; schedule re-audited -- resubmitting identical source.)

typedef __bf16 bf16_t;
typedef __bf16 bf16x8 __attribute__((ext_vector_type(8)));
typedef float  f32x4  __attribute__((ext_vector_type(4)));

#define M_GLOBAL 16384
#define N_GLOBAL 1024
#define K_GLOBAL 2048
#define IN_STRIDE 1024

__device__ __forceinline__ float fast_tanh(float v) {
    float e = __expf(2.0f * v);
    return 1.0f - 2.0f * __builtin_amdgcn_rcpf(e + 1.0f);
}

// ---------------------------------------------------------------------------
// Pass 1: cvt + concat (measured ~6.4 TB/s, at BW ceiling).
// ---------------------------------------------------------------------------
#define XH_UNITS ((long long)M_GLOBAL * K_GLOBAL / 8)
#define W_UNITS  ((long long)N_GLOBAL * K_GLOBAL / 8)

__global__ __launch_bounds__(256)
void cvt_pass(const float* __restrict__ x, const float* __restrict__ h,
              const float* __restrict__ W,
              bf16_t* __restrict__ XHb, bf16_t* __restrict__ Wb)
{
    const long long total = XH_UNITS + W_UNITS;
    for (long long u = (long long)blockIdx.x * 256 + threadIdx.x; u < total;
         u += (long long)gridDim.x * 256) {
        const float* src;
        bf16_t* dst;
        if (u < XH_UNITS) {
            const long long e = u * 8;
            const int row = (int)(e >> 11);
            const int col = (int)(e & 2047);
            src = (col < 1024) ? (x + (long long)row * IN_STRIDE + col)
                               : (h + (long long)row * IN_STRIDE + (col - 1024));
            dst = XHb + e;
        } else {
            const long long e = (u - XH_UNITS) * 8;
            src = W + e;
            dst = Wb + e;
        }
        const float4 v0 = *(const float4*)src;
        const float4 v1 = *(const float4*)(src + 4);
        bf16x8 o;
        o[0] = (bf16_t)v0.x; o[1] = (bf16_t)v0.y;
        o[2] = (bf16_t)v0.z; o[3] = (bf16_t)v0.w;
        o[4] = (bf16_t)v1.x; o[5] = (bf16_t)v1.y;
        o[6] = (bf16_t)v1.z; o[7] = (bf16_t)v1.w;
        *(bf16x8*)dst = o;
    }
}

// ---------------------------------------------------------------------------
// Pass 2: 256x256 8-phase GEMM. 512 threads = 8 waves (2M x 4N), per-wave
// output 128x64. BK=64. LDS: 2 dbuf x {A0,A1,B0,B1} halves of 128x64 bf16
// (16 KB each) = 128 KB. Swizzle: LDS(row, slot16) holds global col-slot
// (slot ^ (row&7)); applied on the global SOURCE address (gload_lds writes
// linearly, rule 21) and on the ds_read address.
// ---------------------------------------------------------------------------
#define NT 32   // K-tiles

__device__ __forceinline__ void gload_lds16(const bf16_t* g, bf16_t* l) {
    __builtin_amdgcn_global_load_lds(
        (const __attribute__((address_space(1))) void*)g,
        (__attribute__((address_space(3))) void*)l, 16, 0, 0);
}

__global__ __launch_bounds__(512, 2)
void gemm8p(const bf16_t* __restrict__ XHb, const bf16_t* __restrict__ Wb,
            const float* __restrict__ bias, float* __restrict__ out)
{
    __shared__ __align__(16) bf16_t lds[2 * 32768];   // 128 KB

    const int tid = threadIdx.x;
    // XCD-aware bijective remap (grid=256, 8 XCDs, 32 blocks each): blocks on
    // one XCD share an n-panel (1 MB Wb slice -> L2-resident).
    const int xcd  = blockIdx.x & 7;
    const int lid  = xcd * 32 + (blockIdx.x >> 3);
    const int bm   = (lid & 63) * 256;
    const int bn   = (lid >> 6) * 256;

    const int lane = tid & 63;
    const int wid  = tid >> 6;
    const int wm = wid >> 2;          // 0..1 (M half)
    const int wn = wid & 3;           // 0..3 (N quarter)
    const int lr = lane & 15;
    const int lk = lane >> 4;
    const int s7 = lr & 7;

    // ---- staging geometry: half-tile = 128 rows x 64 cols (16 KB); each
    // wave stages 2 chunks of 8 rows (1 KB each); lane covers row srow,
    // source col pre-swizzled so linear LDS write == swizzled layout.
    const int srow = lane >> 3;                    // 0..7
    const int scol = ((lane & 7) ^ srow) * 8;      // bf16 elems
    const int c0   = wid * 2;                      // chunks c0, c0+1
    const bf16_t* aS = XHb + (size_t)(bm + c0 * 8 + srow) * K_GLOBAL + scol;
    const bf16_t* bS = Wb  + (size_t)(bn + c0 * 8 + srow) * K_GLOBAL + scol;

    // ---- frag-read bases (elems). dbuf d at d*32768; parts A0,A1,B0,B1 at
    // part*8192. A-half = wm; B-half = wn>>1, within-half row (wn&1)*64+...
    const int aRd = wm * 8192 + lr * 64;
    const int bRd = (2 + (wn >> 1)) * 8192 + ((wn & 1) * 64 + lr) * 64;
    const int sl0 = ((0 + lk) ^ s7) * 8;   // kk=0 swizzled slot
    const int sl1 = ((4 + lk) ^ s7) * 8;   // kk=1

    f32x4 acc[8][4];
#pragma unroll
    for (int i = 0; i < 8; ++i)
#pragma unroll
        for (int j = 0; j < 4; ++j)
            acc[i][j] = (f32x4){0.f, 0.f, 0.f, 0.f};

#define STAGE(D, PART, T) {                                                   \
    const bf16_t* g_ = (((PART) < 2) ? aS : bS)                               \
        + (size_t)(((PART) & 1) * 128) * K_GLOBAL + (T) * 64;                 \
    bf16_t* l_ = lds + (D) * 32768 + (PART) * 8192 + c0 * 512;                \
    gload_lds16(g_, l_);                                                      \
    gload_lds16(g_ + (size_t)8 * K_GLOBAL, l_ + 512);                         \
}

#define BAR() { asm volatile("" ::: "memory");                                \
                __builtin_amdgcn_s_barrier();                                 \
                asm volatile("" ::: "memory"); }
#define VM4() asm volatile("s_waitcnt vmcnt(4)" ::: "memory")
#define VM0() asm volatile("s_waitcnt vmcnt(0)" ::: "memory")

// One phase: ds_reads (B all if FIRSTK, A for mf=M0,M0+1), stage, barrier,
// lgkm-drain (+sched fence, rule 18), setprio-wrapped 16 MFMA. Caller then
// optionally VM4() and always BAR().
#define PHASE(DB, M0, FIRSTK, ...) {                                          \
    const int dbo_ = (DB) * 32768;                                            \
    if (FIRSTK) {                                                             \
        _Pragma("unroll")                                                     \
        for (int nf_ = 0; nf_ < 4; ++nf_) {                                   \
            br[nf_][0] = *(const bf16x8*)(lds + dbo_ + bRd + nf_ * 1024 + sl0); \
            br[nf_][1] = *(const bf16x8*)(lds + dbo_ + bRd + nf_ * 1024 + sl1); \
        }                                                                     \
    }                                                                         \
    bf16x8 a00_ = *(const bf16x8*)(lds + dbo_ + aRd + (M0) * 1024 + sl0);     \
    bf16x8 a01_ = *(const bf16x8*)(lds + dbo_ + aRd + (M0) * 1024 + sl1);     \
    bf16x8 a10_ = *(const bf16x8*)(lds + dbo_ + aRd + ((M0) + 1) * 1024 + sl0); \
    bf16x8 a11_ = *(const bf16x8*)(lds + dbo_ + aRd + ((M0) + 1) * 1024 + sl1); \
    __VA_ARGS__;                                                              \
    asm volatile("" ::: "memory");                                            \
    __builtin_amdgcn_s_barrier();                                             \
    asm volatile("s_waitcnt lgkmcnt(0)" ::: "memory");                        \
    __builtin_amdgcn_sched_barrier(0);                                        \
    __builtin_amdgcn_s_setprio(1);                                            \
    _Pragma("unroll")                                                         \
    for (int nf_ = 0; nf_ < 4; ++nf_) {                                       \
        acc[M0][nf_] = __builtin_amdgcn_mfma_f32_16x16x32_bf16(               \
            a00_, br[nf_][0], acc[M0][nf_], 0, 0, 0);                         \
        acc[M0][nf_] = __builtin_amdgcn_mfma_f32_16x16x32_bf16(               \
            a01_, br[nf_][1], acc[M0][nf_], 0, 0, 0);                         \
        acc[(M0) + 1][nf_] = __builtin_amdgcn_mfma_f32_16x16x32_bf16(         \
            a10_, br[nf_][0], acc[(M0) + 1][nf_], 0, 0, 0);                   \
        acc[(M0) + 1][nf_] = __builtin_amdgcn_mfma_f32_16x16x32_bf16(         \
            a11_, br[nf_][1], acc[(M0) + 1][nf_], 0, 0, 0);                   \
    }                                                                         \
    __builtin_amdgcn_s_setprio(0);                                            \
}

    bf16x8 br[4][2];

    // ---- prologue: T0 all 4 halves -> dbuf0; T1.B0,B1 -> dbuf1 (12 loads).
    STAGE(0, 0, 0); STAGE(0, 1, 0); STAGE(0, 2, 0); STAGE(0, 3, 0);
    STAGE(1, 2, 1); STAGE(1, 3, 1);
    VM4();          // T0 resident; T1.B (newest 4 loads) may remain in flight
    BAR();

    // ---- main loop: iter i computes tiles 2i (dbuf0) and 2i+1 (dbuf1).
    // Stage slots (verified WAR-safe: each target's last reader is >=1
    // barrier-pair earlier):
    //  ph1: T1.A0->d1  ph2: T1.A1->d1  ph3: T2.B0->d0  ph4: T2.B1->d0 [VM4]
    //  ph5: T2.A0->d0  ph6: T2.A1->d0  ph7: T3.B0->d1  ph8: T3.B1->d1 [VM4]
    for (int i = 0; i < 15; ++i) {
        const int T1 = 2 * i + 1, T2 = 2 * i + 2, T3 = 2 * i + 3;
        PHASE(0, 0, 1, STAGE(1, 0, T1));        BAR();
        PHASE(0, 2, 0, STAGE(1, 1, T1));        BAR();
        PHASE(0, 4, 0, STAGE(0, 2, T2));        BAR();
        PHASE(0, 6, 0, STAGE(0, 3, T2)); VM4(); BAR();
        PHASE(1, 0, 1, STAGE(0, 0, T2));        BAR();
        PHASE(1, 2, 0, STAGE(0, 1, T2));        BAR();
        PHASE(1, 4, 0, STAGE(1, 2, T3));        BAR();
        PHASE(1, 6, 0, STAGE(1, 3, T3)); VM4(); BAR();
    }
    // ---- tail: tiles 30 (dbuf0) / 31 (dbuf1); only T31.A still to stage.
    PHASE(0, 0, 1, STAGE(1, 0, 31));        BAR();
    PHASE(0, 2, 0, STAGE(1, 1, 31));        BAR();
    PHASE(0, 4, 0, );                        BAR();
    PHASE(0, 6, 0, ); VM0();                 BAR();
    PHASE(1, 0, 1, );                        BAR();
    PHASE(1, 2, 0, );                        BAR();
    PHASE(1, 4, 0, );                        BAR();
    PHASE(1, 6, 0, );

#undef PHASE
#undef STAGE
#undef BAR
#undef VM4
#undef VM0

    // ---- epilogue: bias + tanh, fp32 store.
    // C/D layout: col = lane&15, row = (lane>>4)*4 + reg (verified r1-r5).
    float bv[4];
#pragma unroll
    for (int nf = 0; nf < 4; ++nf)
        bv[nf] = bias[bn + wn * 64 + nf * 16 + lr];
#pragma unroll
    for (int mf = 0; mf < 8; ++mf) {
#pragma unroll
        for (int nf = 0; nf < 4; ++nf) {
            const int col = bn + wn * 64 + nf * 16 + lr;
#pragma unroll
            for (int r = 0; r < 4; ++r) {
                const int row = bm + wm * 128 + mf * 16 + lk * 4 + r;
                out[(size_t)row * N_GLOBAL + col] = fast_tanh(acc[mf][nf][r] + bv[nf]);
            }
        }
    }
}

// ---------------------------------------------------------------------------
// Fallback (ws too small): round-3 verified fused kernel (~169 us).
// ---------------------------------------------------------------------------
#define FNT 32
__global__ __launch_bounds__(256, 2)
void rnncell_fused(const float* __restrict__ x, const float* __restrict__ h,
                   const float* __restrict__ W, const float* __restrict__ bias,
                   float* __restrict__ out)
{
    __shared__ __align__(16) bf16_t As[2][128 * 64];
    __shared__ __align__(16) bf16_t Bs[2][128 * 64];

    const int tid = threadIdx.x;
    const int bid = blockIdx.x;
    const int bm = (bid >> 3) * 128;
    const int bn = (bid & 7) * 128;

    const int lane = tid & 63;
    const int wid  = tid >> 6;
    const int wr = (wid >> 1) * 64;
    const int wc = (wid & 1) * 64;
    const int lr = lane & 15;
    const int lk = lane >> 4;

    const int row0 = tid >> 3;
    const int sl0  = tid & 7;

    f32x4 acc[4][4];
#pragma unroll
    for (int i = 0; i < 4; ++i)
#pragma unroll
        for (int j = 0; j < 4; ++j)
            acc[i][j] = (f32x4){0.f, 0.f, 0.f, 0.f};

    float4 la[4][2], lb[4][2];

#define F_LOAD_A(T) do {                                                      \
    const int k0_ = (T) * 64;                                                 \
    const float* sA_ = (k0_ < 1024)                                           \
        ? (x + (size_t)bm * IN_STRIDE + k0_)                                  \
        : (h + (size_t)bm * IN_STRIDE + (k0_ - 1024));                        \
    _Pragma("unroll")                                                         \
    for (int i_ = 0; i_ < 4; ++i_) {                                          \
        const float* pa_ = sA_ + (size_t)(row0 + i_ * 32) * IN_STRIDE + sl0 * 8; \
        la[i_][0] = *(const float4*)(pa_);                                    \
        la[i_][1] = *(const float4*)(pa_ + 4);                                \
    }                                                                         \
} while (0)

#define F_LOAD_B(T) do {                                                      \
    const float* sB_ = W + (size_t)bn * K_GLOBAL + (T) * 64;                  \
    _Pragma("unroll")                                                         \
    for (int i_ = 0; i_ < 4; ++i_) {                                          \
        const float* pb_ = sB_ + (size_t)(row0 + i_ * 32) * K_GLOBAL + sl0 * 8; \
        lb[i_][0] = *(const float4*)(pb_);                                    \
        lb[i_][1] = *(const float4*)(pb_ + 4);                                \
    }                                                                         \
} while (0)

    F_LOAD_A(0);
    F_LOAD_B(0);

    for (int t = 0; t < FNT; ++t) {
        bf16_t* __restrict__ Ab = As[t & 1];
        bf16_t* __restrict__ Bb = Bs[t & 1];

#pragma unroll
        for (int i = 0; i < 4; ++i) {
            const int row = row0 + i * 32;
            const int ssl = sl0 ^ (row & 7);
            bf16x8 va;
            va[0] = (bf16_t)la[i][0].x; va[1] = (bf16_t)la[i][0].y;
            va[2] = (bf16_t)la[i][0].z; va[3] = (bf16_t)la[i][0].w;
            va[4] = (bf16_t)la[i][1].x; va[5] = (bf16_t)la[i][1].y;
            va[6] = (bf16_t)la[i][1].z; va[7] = (bf16_t)la[i][1].w;
            *(bf16x8*)(Ab + row * 64 + ssl * 8) = va;
        }
#pragma unroll
        for (int i = 0; i < 4; ++i) {
            const int row = row0 + i * 32;
            const int ssl = sl0 ^ (row & 7);
            bf16x8 vb;
            vb[0] = (bf16_t)lb[i][0].x; vb[1] = (bf16_t)lb[i][0].y;
            vb[2] = (bf16_t)lb[i][0].z; vb[3] = (bf16_t)lb[i][0].w;
            vb[4] = (bf16_t)lb[i][1].x; vb[5] = (bf16_t)lb[i][1].y;
            vb[6] = (bf16_t)lb[i][1].z; vb[7] = (bf16_t)lb[i][1].w;
            *(bf16x8*)(Bb + row * 64 + ssl * 8) = vb;
        }

        __syncthreads();

        if (t + 1 < FNT) F_LOAD_A(t + 1);

#pragma unroll
        for (int kk = 0; kk < 2; ++kk) {
            bf16x8 af[4], bfr[4];
#pragma unroll
            for (int mf = 0; mf < 4; ++mf) {
                const int row = wr + mf * 16 + lr;
                const int sl  = (kk * 4 + lk) ^ (row & 7);
                af[mf] = *(const bf16x8*)(Ab + row * 64 + sl * 8);
            }
#pragma unroll
            for (int nf = 0; nf < 4; ++nf) {
                const int row = wc + nf * 16 + lr;
                const int sl  = (kk * 4 + lk) ^ (row & 7);
                bfr[nf] = *(const bf16x8*)(Bb + row * 64 + sl * 8);
            }
#pragma unroll
            for (int mf = 0; mf < 4; ++mf)
#pragma unroll
                for (int nf = 0; nf < 4; ++nf)
                    acc[mf][nf] = __builtin_amdgcn_mfma_f32_16x16x32_bf16(
                        af[mf], bfr[nf], acc[mf][nf], 0, 0, 0);
        }

        if (t + 1 < FNT) F_LOAD_B(t + 1);
    }
#undef F_LOAD_A
#undef F_LOAD_B

    float bv[4];
#pragma unroll
    for (int nf = 0; nf < 4; ++nf)
        bv[nf] = bias[bn + wc + nf * 16 + lr];
#pragma unroll
    for (int mf = 0; mf < 4; ++mf) {
#pragma unroll
        for (int nf = 0; nf < 4; ++nf) {
            const int col = bn + wc + nf * 16 + lr;
#pragma unroll
            for (int r = 0; r < 4; ++r) {
                const int row = bm + wr + mf * 16 + lk * 4 + r;
                out[(size_t)row * N_GLOBAL + col] = fast_tanh(acc[mf][nf][r] + bv[nf]);
            }
        }
    }
}

extern "C" void kernel_launch(void* const* d_in, const int* in_sizes, int n_in,
                              void* d_out, int out_size, void* d_ws, size_t ws_size,
                              hipStream_t stream) {
    (void)in_sizes; (void)n_in; (void)out_size;
    const float* x = (const float*)d_in[0];
    const float* h = (const float*)d_in[1];
    const float* W = (const float*)d_in[2];
    const float* b = (const float*)d_in[3];
    float* out = (float*)d_out;

    const size_t need = ((size_t)M_GLOBAL + N_GLOBAL) * K_GLOBAL * sizeof(bf16_t);
    if (ws_size >= need) {
        bf16_t* XHb = (bf16_t*)d_ws;
        bf16_t* Wb  = XHb + (size_t)M_GLOBAL * K_GLOBAL;
        cvt_pass<<<2048, 256, 0, stream>>>(x, h, W, XHb, Wb);
        gemm8p<<<256, 512, 0, stream>>>(XHb, Wb, b, out);
    } else {
        rnncell_fused<<<1024, 256, 0, stream>>>(x, h, W, b, out);
    }
}